// Round 5
// baseline (120.564 us; speedup 1.0000x reference)
//
#include <hip/hip_runtime.h>

// Problem constants (from reference): B=8, H=1024, NIN=256, C=128, E=16
#define B_    8
#define H_    1024
#define NIN_  256
#define C_    128
#define E_    16

// clang native 4-float vector — required by __builtin_nontemporal_load/store
typedef float f4_t __attribute__((ext_vector_type(4)));

// ---------------------------------------------------------------------------
// Kernel 1 (v2): s_t[b,h] = sum_n vt[n]*x[b,n,h];  s_p likewise with vp.
//   vt[n] = sum_c Wcat[E+c]*Wt[c,n],  vp[n] = sum_c Wcat[E+C+c]*Wp[c,n]
// Grid: 512 blocks (b, h-chunk of 16 float4 = 64 h), 256 threads.
//   Phase A: thread n computes vt[n], vp[n] (coalesced W column reads).
//   Phase B: lane group (hq = tid&15 -> float4 column, ng = tid>>4 -> 16 n's)
//            f4 loads of x; LDS tree-reduce over the 16 n-groups.
// ---------------------------------------------------------------------------
__global__ __launch_bounds__(256) void compute_s_kernel(
    const float* __restrict__ x,     // (B, NIN, H)
    const float* __restrict__ Wt,    // (C, NIN)
    const float* __restrict__ Wp,    // (C, NIN)
    const float* __restrict__ Wcat,  // (E + 2C,)
    float* __restrict__ s_t,         // (B, H)
    float* __restrict__ s_p)         // (B, H)
{
    __shared__ float vt[NIN_];
    __shared__ float vp[NIN_];
    __shared__ f4_t red_t[16][16];   // [ng][hq]
    __shared__ f4_t red_p[16][16];

    const int tid = threadIdx.x;

    // Phase A: fold Wcat into W columns. tid == n.
    {
        float at = 0.f, ap = 0.f;
        #pragma unroll 4
        for (int c = 0; c < C_; ++c) {
            at += Wcat[E_ + c]      * Wt[c * NIN_ + tid];
            ap += Wcat[E_ + C_ + c] * Wp[c * NIN_ + tid];
        }
        vt[tid] = at;
        vp[tid] = ap;
    }
    __syncthreads();

    // Phase B: block = (b, 64-h chunk). 512 blocks = 8 b * 64 chunks... no:
    // 16 chunks of 64 h per b -> need h-chunk = H/ (512/B) = 16 f4 = 64 h.
    const int b   = blockIdx.x >> 6;          // 64 blocks per b
    const int hq0 = (blockIdx.x & 63) << 2;   // first float4 col (4 f4 = 16 h)
    const int hq  = hq0 + (tid & 3);          // this thread's float4 column
    const int ng  = tid >> 2;                 // 0..63: n-group (4 n each)

    const f4_t* x4 = (const f4_t*)x + (size_t)b * NIN_ * (H_ / 4) + hq;
    f4_t at = {0.f, 0.f, 0.f, 0.f}, ap = at;
    const int n0 = ng << 2;
    #pragma unroll
    for (int k = 0; k < 4; ++k) {
        const int n = n0 + k;
        const f4_t xv = x4[(size_t)n * (H_ / 4)];
        at += vt[n] * xv;
        ap += vp[n] * xv;
    }
    // reduce over 64 n-groups: LDS, 4 stages of 4-way
    __shared__ f4_t rt[64][4];
    __shared__ f4_t rp[64][4];
    rt[ng][tid & 3] = at;
    rp[ng][tid & 3] = ap;
    __syncthreads();
    if (ng < 16) {   // 64 threads: each sums 4 groups for its (hq) column... 
        // thread t (0..63): column = t&3, target group gg = t>>2 (16 of them)
        const int col = tid & 3;
        const int gg  = tid >> 2;
        f4_t st = rt[gg * 4 + 0][col] + rt[gg * 4 + 1][col]
                + rt[gg * 4 + 2][col] + rt[gg * 4 + 3][col];
        f4_t sp = rp[gg * 4 + 0][col] + rp[gg * 4 + 1][col]
                + rp[gg * 4 + 2][col] + rp[gg * 4 + 3][col];
        rt[gg][col] = st;   // safe: writes to [0..15], reads were [0..63]
        rp[gg][col] = sp;
    }
    __syncthreads();
    if (tid < 4) {   // 4 threads finish 4 columns
        const int col = tid;
        f4_t st = {0.f,0.f,0.f,0.f}, sp = st;
        #pragma unroll
        for (int g = 0; g < 16; ++g) { st += rt[g][col]; sp += rp[g][col]; }
        ((f4_t*)s_t)[b * (H_ / 4) + hq0 + col] = st;
        ((f4_t*)s_p)[b * (H_ / 4) + hq0 + col] = sp;
    }
}

// ---------------------------------------------------------------------------
// Kernel 2: out[b,h,w] = sum_e Wcat[e]*edges[b,e,h,w] + s_t[b,h] + s_p[b,w]
// R3 geometry (best measured): 1024 blocks x 256 thr, 32 KB bursts/stream.
// Loads cached (no nt — A/B vs R3's nt loads); stores stay nontemporal.
// ---------------------------------------------------------------------------
#define R_    8              // h-rows (256-float4 chunks) per block
#define HH4_  (H_ * H_ / 4)  // 262144 float4 per (b,e) plane

__global__ __launch_bounds__(256) void affinity_main_kernel(
    const float* __restrict__ edges,  // (B, E, H, H)
    const float* __restrict__ Wcat,   // first E entries = w_e
    const float* __restrict__ s_t,    // (B, H)
    const float* __restrict__ s_p,    // (B, H)
    float* __restrict__ out)          // (B, H, H) flat
{
    const int tid  = threadIdx.x;
    const int bid  = blockIdx.x;          // 0 .. 1023
    const int b    = bid >> 7;            // 128 chunks per b
    const int rem0 = (bid & 127) << 11;   // chunk start, in float4 units
    const int h0   = rem0 >> 8;           // first h-row of this chunk (8 rows)

    float we[E_];
    #pragma unroll
    for (int e = 0; e < E_; ++e) we[e] = Wcat[e];

    const f4_t sp = ((const f4_t*)s_p)[b * (H_ / 4) + tid];
    f4_t acc[R_];
    #pragma unroll
    for (int r = 0; r < R_; ++r) {
        const float st = s_t[b * H_ + h0 + r];   // uniform across wave
        acc[r] = sp + st;
    }

    const f4_t* ebase = (const f4_t*)edges
                      + (size_t)b * E_ * HH4_ + rem0 + tid;

    #pragma unroll
    for (int e = 0; e < E_; ++e) {
        const f4_t* pe = ebase + (size_t)e * HH4_;
        f4_t ev[R_];
        #pragma unroll
        for (int r = 0; r < R_; ++r)
            ev[r] = pe[r * 256];               // cached loads this round
        #pragma unroll
        for (int r = 0; r < R_; ++r)
            acc[r] += we[e] * ev[r];
    }

    f4_t* o = (f4_t*)out + (size_t)b * HH4_ + rem0 + tid;
    #pragma unroll
    for (int r = 0; r < R_; ++r)
        __builtin_nontemporal_store(acc[r], &o[r * 256]);
}

extern "C" void kernel_launch(void* const* d_in, const int* in_sizes, int n_in,
                              void* d_out, int out_size, void* d_ws, size_t ws_size,
                              hipStream_t stream) {
    // Inputs: 0 adj (unused), 1 edges, 2 x, 3 Wt, 4 Wp, 5 Wcat
    const float* edges = (const float*)d_in[1];
    const float* x     = (const float*)d_in[2];
    const float* Wt    = (const float*)d_in[3];
    const float* Wp    = (const float*)d_in[4];
    const float* Wcat  = (const float*)d_in[5];
    float* out = (float*)d_out;

    float* s_t = (float*)d_ws;            // B*H floats = 32 KB
    float* s_p = s_t + B_ * H_;           // B*H floats = 32 KB

    compute_s_kernel<<<512, 256, 0, stream>>>(x, Wt, Wp, Wcat, s_t, s_p);

    affinity_main_kernel<<<1024, 256, 0, stream>>>(edges, Wcat, s_t, s_p, out);
}

// Round 6
// 107.578 us; speedup vs baseline: 1.1207x; 1.1207x over previous
//
#include <hip/hip_runtime.h>

// Problem constants (from reference): B=8, H=1024, NIN=256, C=128, E=16
#define B_    8
#define H_    1024
#define NIN_  256
#define C_    128
#define E_    16

// clang native 4-float vector — required by __builtin_nontemporal_load/store
typedef float f4_t __attribute__((ext_vector_type(4)));

// ---------------------------------------------------------------------------
// Kernel 1 (v2): s_t[b,h] = sum_n vt[n]*x[b,n,h];  s_p likewise with vp.
//   vt[n] = sum_c Wcat[E+c]*Wt[c,n],  vp[n] = sum_c Wcat[E+C+c]*Wp[c,n]
// Grid: 512 blocks x 256 thr. Block = (b, 16-h chunk of 4 float4 columns).
//   Phase A: thread n computes vt[n], vp[n] (coalesced W column reads).
//   Phase B: thread (col = tid&3, ng = tid>>2) accumulates 4 n's for one
//            float4 column (vectorized x loads); two-stage LDS reduce.
// ---------------------------------------------------------------------------
__global__ __launch_bounds__(256) void compute_s_kernel(
    const float* __restrict__ x,     // (B, NIN, H)
    const float* __restrict__ Wt,    // (C, NIN)
    const float* __restrict__ Wp,    // (C, NIN)
    const float* __restrict__ Wcat,  // (E + 2C,)
    float* __restrict__ s_t,         // (B, H)
    float* __restrict__ s_p)         // (B, H)
{
    __shared__ float vt[NIN_];
    __shared__ float vp[NIN_];
    __shared__ f4_t rt[64][4];
    __shared__ f4_t rp[64][4];

    const int tid = threadIdx.x;

    // Phase A: fold Wcat into W columns. tid == n.
    {
        float at = 0.f, ap = 0.f;
        #pragma unroll 4
        for (int c = 0; c < C_; ++c) {
            at += Wcat[E_ + c]      * Wt[c * NIN_ + tid];
            ap += Wcat[E_ + C_ + c] * Wp[c * NIN_ + tid];
        }
        vt[tid] = at;
        vp[tid] = ap;
    }
    __syncthreads();

    // Phase B
    const int b   = blockIdx.x >> 6;          // 64 blocks per b
    const int hq0 = (blockIdx.x & 63) << 2;   // first float4 col of this chunk
    const int col = tid & 3;
    const int hq  = hq0 + col;                // this thread's float4 column
    const int ng  = tid >> 2;                 // 0..63: n-group (4 n each)

    const f4_t* x4 = (const f4_t*)x + (size_t)b * NIN_ * (H_ / 4) + hq;
    f4_t at = {0.f, 0.f, 0.f, 0.f}, ap = at;
    const int n0 = ng << 2;
    #pragma unroll
    for (int k = 0; k < 4; ++k) {
        const int n = n0 + k;
        const f4_t xv = x4[(size_t)n * (H_ / 4)];
        at += vt[n] * xv;
        ap += vp[n] * xv;
    }
    rt[ng][col] = at;
    rp[ng][col] = ap;
    __syncthreads();

    if (tid < 64) {   // stage 1: 64 -> 16 groups
        const int c1 = tid & 3;
        const int gg = tid >> 2;
        f4_t st = rt[gg * 4 + 0][c1] + rt[gg * 4 + 1][c1]
                + rt[gg * 4 + 2][c1] + rt[gg * 4 + 3][c1];
        f4_t sp = rp[gg * 4 + 0][c1] + rp[gg * 4 + 1][c1]
                + rp[gg * 4 + 2][c1] + rp[gg * 4 + 3][c1];
        rt[gg][c1] = st;
        rp[gg][c1] = sp;
    }
    __syncthreads();

    if (tid < 4) {    // stage 2: finish 4 columns
        f4_t st = {0.f, 0.f, 0.f, 0.f}, sp = st;
        #pragma unroll
        for (int g = 0; g < 16; ++g) { st += rt[g][tid]; sp += rp[g][tid]; }
        ((f4_t*)s_t)[b * (H_ / 4) + hq0 + tid] = st;
        ((f4_t*)s_p)[b * (H_ / 4) + hq0 + tid] = sp;
    }
}

// ---------------------------------------------------------------------------
// Kernel 2: out[b,h,w] = sum_e Wcat[e]*edges[b,e,h,w] + s_t[b,h] + s_p[b,w]
// R3 configuration exactly (best measured, ~95us @ ~6.0 TB/s):
//   1024 blocks x 256 thr; each block owns a contiguous 32 KB chunk (8 h-rows)
//   per e-plane, issuing 8 back-to-back wave-loads per stream.
//   NONTEMPORAL on BOTH loads and stores — measured +16% vs cached loads (R5).
// ---------------------------------------------------------------------------
#define R_    8              // h-rows (256-float4 chunks) per block
#define HH4_  (H_ * H_ / 4)  // 262144 float4 per (b,e) plane

__global__ __launch_bounds__(256) void affinity_main_kernel(
    const float* __restrict__ edges,  // (B, E, H, H)
    const float* __restrict__ Wcat,   // first E entries = w_e
    const float* __restrict__ s_t,    // (B, H)
    const float* __restrict__ s_p,    // (B, H)
    float* __restrict__ out)          // (B, H, H) flat
{
    const int tid  = threadIdx.x;
    const int bid  = blockIdx.x;          // 0 .. 1023
    const int b    = bid >> 7;            // 128 chunks per b
    const int rem0 = (bid & 127) << 11;   // chunk start, in float4 units
    const int h0   = rem0 >> 8;           // first h-row of this chunk (8 rows)

    float we[E_];
    #pragma unroll
    for (int e = 0; e < E_; ++e) we[e] = Wcat[e];

    const f4_t sp = ((const f4_t*)s_p)[b * (H_ / 4) + tid];
    f4_t acc[R_];
    #pragma unroll
    for (int r = 0; r < R_; ++r) {
        const float st = s_t[b * H_ + h0 + r];   // uniform across wave
        acc[r] = sp + st;
    }

    const f4_t* ebase = (const f4_t*)edges
                      + (size_t)b * E_ * HH4_ + rem0 + tid;

    #pragma unroll
    for (int e = 0; e < E_; ++e) {
        const f4_t* pe = ebase + (size_t)e * HH4_;
        f4_t ev[R_];
        #pragma unroll
        for (int r = 0; r < R_; ++r)
            ev[r] = __builtin_nontemporal_load(&pe[r * 256]);
        #pragma unroll
        for (int r = 0; r < R_; ++r)
            acc[r] += we[e] * ev[r];
    }

    f4_t* o = (f4_t*)out + (size_t)b * HH4_ + rem0 + tid;
    #pragma unroll
    for (int r = 0; r < R_; ++r)
        __builtin_nontemporal_store(acc[r], &o[r * 256]);
}

extern "C" void kernel_launch(void* const* d_in, const int* in_sizes, int n_in,
                              void* d_out, int out_size, void* d_ws, size_t ws_size,
                              hipStream_t stream) {
    // Inputs: 0 adj (unused), 1 edges, 2 x, 3 Wt, 4 Wp, 5 Wcat
    const float* edges = (const float*)d_in[1];
    const float* x     = (const float*)d_in[2];
    const float* Wt    = (const float*)d_in[3];
    const float* Wp    = (const float*)d_in[4];
    const float* Wcat  = (const float*)d_in[5];
    float* out = (float*)d_out;

    float* s_t = (float*)d_ws;            // B*H floats = 32 KB
    float* s_p = s_t + B_ * H_;           // B*H floats = 32 KB

    compute_s_kernel<<<512, 256, 0, stream>>>(x, Wt, Wp, Wcat, s_t, s_p);

    affinity_main_kernel<<<1024, 256, 0, stream>>>(edges, Wcat, s_t, s_p, out);
}

// Round 7
// 100.600 us; speedup vs baseline: 1.1985x; 1.0694x over previous
//
#include <hip/hip_runtime.h>

// Problem constants (from reference): B=8, H=1024, NIN=256, C=128, E=16
#define B_    8
#define H_    1024
#define NIN_  256
#define C_    128
#define E_    16

// clang native 4-float vector — required by __builtin_nontemporal_load/store
typedef float f4_t __attribute__((ext_vector_type(4)));

// ---------------------------------------------------------------------------
// Kernel 1 (v3): s_t[b,h] = sum_n vt[n]*x[b,n,h];  s_p likewise with vp.
//   vt[n] = sum_c Wcat[E+c]*Wt[c,n],  vp[n] = sum_c Wcat[E+C+c]*Wp[c,n]
// v1's proven geometry (128 blocks — Phase A redundancy stays at 33 MB) with
// f4-vectorized phase B (16 iter/thread vs 64) + two-stage LDS reduce.
// Block = (b, 64-h chunk) = 16 f4 columns; thread (hq=tid&15, ng=tid>>4).
// ---------------------------------------------------------------------------
__global__ __launch_bounds__(256) void compute_s_kernel(
    const float* __restrict__ x,     // (B, NIN, H)
    const float* __restrict__ Wt,    // (C, NIN)
    const float* __restrict__ Wp,    // (C, NIN)
    const float* __restrict__ Wcat,  // (E + 2C,)
    float* __restrict__ s_t,         // (B, H)
    float* __restrict__ s_p)         // (B, H)
{
    __shared__ float vt[NIN_];
    __shared__ float vp[NIN_];
    __shared__ f4_t rt[16][16];      // [ng][hq]
    __shared__ f4_t rp[16][16];
    __shared__ f4_t rt2[4][16];
    __shared__ f4_t rp2[4][16];

    const int tid = threadIdx.x;

    // Phase A: fold Wcat into W columns. tid == n (coalesced across tid).
    {
        float at = 0.f, ap = 0.f;
        #pragma unroll 4
        for (int c = 0; c < C_; ++c) {
            at += Wcat[E_ + c]      * Wt[c * NIN_ + tid];
            ap += Wcat[E_ + C_ + c] * Wp[c * NIN_ + tid];
        }
        vt[tid] = at;
        vp[tid] = ap;
    }
    __syncthreads();

    // Phase B: f4 loads. x viewed as (B, NIN, H/4) f4.
    const int b   = blockIdx.x >> 4;           // 16 chunks per b
    const int hq0 = (blockIdx.x & 15) << 4;    // first f4 column (16 per chunk)
    const int hq  = hq0 + (tid & 15);
    const int ng  = tid >> 4;                  // 0..15, 16 n each

    const f4_t* x4 = (const f4_t*)x + (size_t)b * NIN_ * (H_ / 4) + hq;
    f4_t at = {0.f, 0.f, 0.f, 0.f}, ap = at;
    const int n0 = ng << 4;
    #pragma unroll
    for (int k = 0; k < 16; ++k) {
        const int n = n0 + k;
        const f4_t xv = x4[(size_t)n * (H_ / 4)];
        at += vt[n] * xv;
        ap += vp[n] * xv;
    }
    rt[ng][tid & 15] = at;
    rp[ng][tid & 15] = ap;
    __syncthreads();

    if (tid < 64) {   // stage 1: 16 -> 4 partials per column
        const int c1 = tid & 15;
        const int q  = tid >> 4;
        rt2[q][c1] = rt[q * 4 + 0][c1] + rt[q * 4 + 1][c1]
                   + rt[q * 4 + 2][c1] + rt[q * 4 + 3][c1];
        rp2[q][c1] = rp[q * 4 + 0][c1] + rp[q * 4 + 1][c1]
                   + rp[q * 4 + 2][c1] + rp[q * 4 + 3][c1];
    }
    __syncthreads();

    if (tid < 16) {   // stage 2: finish
        const f4_t st = rt2[0][tid] + rt2[1][tid] + rt2[2][tid] + rt2[3][tid];
        const f4_t sp = rp2[0][tid] + rp2[1][tid] + rp2[2][tid] + rp2[3][tid];
        ((f4_t*)s_t)[b * (H_ / 4) + hq0 + tid] = st;
        ((f4_t*)s_p)[b * (H_ / 4) + hq0 + tid] = sp;
    }
}

// ---------------------------------------------------------------------------
// Kernel 2: out[b,h,w] = sum_e Wcat[e]*edges[b,e,h,w] + s_t[b,h] + s_p[b,w]
// R3 configuration exactly (best measured, ~95us @ ~6.0 TB/s):
//   1024 blocks x 256 thr; each block owns a contiguous 32 KB chunk (8 h-rows)
//   per e-plane, issuing 8 back-to-back wave-loads per stream.
//   NONTEMPORAL on BOTH loads and stores — measured +16% vs cached loads (R5).
// ---------------------------------------------------------------------------
#define R_    8              // h-rows (256-float4 chunks) per block
#define HH4_  (H_ * H_ / 4)  // 262144 float4 per (b,e) plane

__global__ __launch_bounds__(256) void affinity_main_kernel(
    const float* __restrict__ edges,  // (B, E, H, H)
    const float* __restrict__ Wcat,   // first E entries = w_e
    const float* __restrict__ s_t,    // (B, H)
    const float* __restrict__ s_p,    // (B, H)
    float* __restrict__ out)          // (B, H, H) flat
{
    const int tid  = threadIdx.x;
    const int bid  = blockIdx.x;          // 0 .. 1023
    const int b    = bid >> 7;            // 128 chunks per b
    const int rem0 = (bid & 127) << 11;   // chunk start, in float4 units
    const int h0   = rem0 >> 8;           // first h-row of this chunk (8 rows)

    float we[E_];
    #pragma unroll
    for (int e = 0; e < E_; ++e) we[e] = Wcat[e];

    const f4_t sp = ((const f4_t*)s_p)[b * (H_ / 4) + tid];
    f4_t acc[R_];
    #pragma unroll
    for (int r = 0; r < R_; ++r) {
        const float st = s_t[b * H_ + h0 + r];   // uniform across wave
        acc[r] = sp + st;
    }

    const f4_t* ebase = (const f4_t*)edges
                      + (size_t)b * E_ * HH4_ + rem0 + tid;

    #pragma unroll
    for (int e = 0; e < E_; ++e) {
        const f4_t* pe = ebase + (size_t)e * HH4_;
        f4_t ev[R_];
        #pragma unroll
        for (int r = 0; r < R_; ++r)
            ev[r] = __builtin_nontemporal_load(&pe[r * 256]);
        #pragma unroll
        for (int r = 0; r < R_; ++r)
            acc[r] += we[e] * ev[r];
    }

    f4_t* o = (f4_t*)out + (size_t)b * HH4_ + rem0 + tid;
    #pragma unroll
    for (int r = 0; r < R_; ++r)
        __builtin_nontemporal_store(acc[r], &o[r * 256]);
}

extern "C" void kernel_launch(void* const* d_in, const int* in_sizes, int n_in,
                              void* d_out, int out_size, void* d_ws, size_t ws_size,
                              hipStream_t stream) {
    // Inputs: 0 adj (unused), 1 edges, 2 x, 3 Wt, 4 Wp, 5 Wcat
    const float* edges = (const float*)d_in[1];
    const float* x     = (const float*)d_in[2];
    const float* Wt    = (const float*)d_in[3];
    const float* Wp    = (const float*)d_in[4];
    const float* Wcat  = (const float*)d_in[5];
    float* out = (float*)d_out;

    float* s_t = (float*)d_ws;            // B*H floats = 32 KB
    float* s_p = s_t + B_ * H_;           // B*H floats = 32 KB

    compute_s_kernel<<<B_ * (H_ / 64), 256, 0, stream>>>(x, Wt, Wp, Wcat, s_t, s_p);

    affinity_main_kernel<<<1024, 256, 0, stream>>>(edges, Wcat, s_t, s_p, out);
}